// Round 8
// baseline (120.925 us; speedup 1.0000x reference)
//
#include <hip/hip_runtime.h>
#include <math.h>

static constexpr int B_ = 32, M_ = 100, L_ = 30, LQ_ = 30, E_ = 256, V_ = 32000;

// ---------------- Kernel 1: story embeddings (fused 4 tables; known-66us L2-fill wall).
// One block per (b,m); wave w = table w; 64 lanes x float4 = one contiguous 1KB row gather.
__global__ __launch_bounds__(256) void k_embed(const int* __restrict__ trainS,
                                               const float* __restrict__ A1,
                                               const float* __restrict__ A2,
                                               const float* __restrict__ A3,
                                               const float* __restrict__ A4,
                                               float* __restrict__ embA) {
    const int bm = blockIdx.x;
    const int tbl = threadIdx.x >> 6;
    const int e0 = (threadIdx.x & 63) * 4;
    const float* __restrict__ A = (tbl == 0) ? A1 : (tbl == 1) ? A2 : (tbl == 2) ? A3 : A4;
    const float half_e = (E_ + 1) * 0.5f;
    const float half_j = (L_ + 1) * 0.5f;
    const float inv = 1.0f / (float)(E_ * L_);
    const float k0 = (float)(e0 + 1) - half_e;
    const float k1 = k0 + 1.f, k2 = k0 + 2.f, k3 = k0 + 3.f;

    int idx[L_];
#pragma unroll
    for (int l = 0; l < L_; ++l) idx[l] = trainS[bm * L_ + l];  // uniform -> s_load

    float4 acc = make_float4(0.f, 0.f, 0.f, 0.f);
#pragma unroll
    for (int c = 0; c < 2; ++c) {
        float4 r[15];
#pragma unroll
        for (int j = 0; j < 15; ++j)
            r[j] = *reinterpret_cast<const float4*>(A + (size_t)idx[c * 15 + j] * E_ + e0);
        __builtin_amdgcn_sched_barrier(0);
#pragma unroll
        for (int j = 0; j < 15; ++j) {
            const int l = c * 15 + j;
            const float coef = 4.0f * ((float)(l + 1) - half_j) * inv;
            acc.x += r[j].x * (1.0f + coef * k0);
            acc.y += r[j].y * (1.0f + coef * k1);
            acc.z += r[j].z * (1.0f + coef * k2);
            acc.w += r[j].w * (1.0f + coef * k3);
        }
    }
    *reinterpret_cast<float4*>(embA + (size_t)tbl * (B_ * M_ * E_) + (size_t)bm * E_ + e0) = acc;
}

// ---------------- Kernel 2: query embedding + three hops. One 1024-thread block per b.
// Writes u TRANSPOSED u_T[e*B + b]; zeroes partial[b*8..b*8+7].
__global__ __launch_bounds__(1024) void k_hops(const int* __restrict__ trainQ,
                                               const float* __restrict__ trainQM,
                                               const float* __restrict__ A1,
                                               const float* __restrict__ embA,
                                               const float* __restrict__ trainPM,
                                               float* __restrict__ u_T,
                                               float* __restrict__ partial) {
    const int b = blockIdx.x;
    const int tid = threadIdx.x;
    const int lane = tid & 63;
    const int wave = tid >> 6;
    const int g = tid >> 8;
    const int e = tid & 255;
    if (tid < 8) partial[b * 8 + tid] = 0.f;
    __shared__ float u_sh[E_];
    __shared__ float sc[M_];
    __shared__ float p_sh[M_];
    __shared__ float osum[4][E_];

    {
        const float half_e = (E_ + 1) * 0.5f;
        const float half_j = (LQ_ + 1) * 0.5f;
        const float inv = 1.0f / (float)(E_ * LQ_);
        const float ke = (float)(e + 1) - half_e;
        const int l0 = g * 8;
        const int ln = (LQ_ - l0 < 8) ? (LQ_ - l0) : 8;
        int qi[8];
        float qm[8];
#pragma unroll
        for (int j = 0; j < 8; ++j) {
            if (j < ln) {
                qi[j] = trainQ[b * LQ_ + l0 + j];
                qm[j] = trainQM[b * LQ_ + l0 + j];
            } else { qi[j] = 0; qm[j] = 0.f; }
        }
        float r[8];
#pragma unroll
        for (int j = 0; j < 8; ++j)
            r[j] = (j < ln) ? A1[(size_t)qi[j] * E_ + e] : 0.f;
        float part = 0.f;
#pragma unroll
        for (int j = 0; j < 8; ++j) {
            const float pe = 1.0f + 4.0f * ke * ((float)(l0 + j + 1) - half_j) * inv;
            part += r[j] * pe * qm[j];
        }
        osum[g][e] = part;
    }
    __syncthreads();
    if (tid < E_) u_sh[tid] = osum[0][tid] + osum[1][tid] + osum[2][tid] + osum[3][tid];
    __syncthreads();

    for (int hop = 0; hop < 3; ++hop) {
        const float* memA = embA + (size_t)hop * (B_ * M_ * E_) + (size_t)b * M_ * E_;
        const float* memC = memA + (size_t)(B_ * M_ * E_);
#pragma unroll 2
        for (int m = wave; m < M_; m += 16) {
            const float* row = memA + m * E_;
            float part = 0.f;
#pragma unroll
            for (int j = 0; j < 4; ++j)
                part += row[lane + 64 * j] * u_sh[lane + 64 * j];
#pragma unroll
            for (int off = 32; off > 0; off >>= 1)
                part += __shfl_xor(part, off, 64);
            if (lane == 0) sc[m] = part * trainPM[b * M_ + m];
        }
        __syncthreads();
        if (wave == 0) {
            const float pm0 = (lane < M_) ? trainPM[b * M_ + lane] : 0.f;
            const float pm1 = (lane + 64 < M_) ? trainPM[b * M_ + lane + 64] : 0.f;
            const float x0 = (lane < M_ && pm0 > 0.f) ? sc[lane] : -1e30f;
            const float x1 = (lane + 64 < M_ && pm1 > 0.f) ? sc[lane + 64] : -1e30f;
            float mx = fmaxf(x0, x1);
#pragma unroll
            for (int off = 32; off > 0; off >>= 1)
                mx = fmaxf(mx, __shfl_xor(mx, off, 64));
            const float e0v = (lane < M_) ? expf(x0 - mx) * pm0 : 0.f;
            const float e1v = (lane + 64 < M_) ? expf(x1 - mx) * pm1 : 0.f;
            float ssum = e0v + e1v;
#pragma unroll
            for (int off = 32; off > 0; off >>= 1)
                ssum += __shfl_xor(ssum, off, 64);
            const float invs = 1.0f / (ssum + 1e-13f);
            if (lane < M_) p_sh[lane] = e0v * invs;
            if (lane + 64 < M_) p_sh[lane + 64] = e1v * invs;
        }
        __syncthreads();
        {
            float acc = 0.f;
            const float* crow = memC + e;
            const int m0 = g * 25;
#pragma unroll 5
            for (int mm = 0; mm < 25; ++mm)
                acc += p_sh[m0 + mm] * crow[(size_t)(m0 + mm) * E_];
            osum[g][e] = acc;
        }
        __syncthreads();
        if (tid < E_) u_sh[tid] += osum[0][tid] + osum[1][tid] + osum[2][tid] + osum[3][tid];
        __syncthreads();
    }
    if (tid < E_) u_T[tid * B_ + b] = u_sh[tid];
}

// ---------------- Kernel 3: wx = u @ W.T + b; batch-LN; z = y + log(VM); exp-partials.
// 1000 blocks x 256 thr; 32 v/block; thread = (vl = tid>>3, bg = tid&7): 1 v x 4 b.
// W double-buffered in regs (wA/wB), no sched_barrier -> next chunk flies under FMAs.
// u_T in LDS [e][b]: ds_read_b128 conflict-free (8 bg banks x 4-lane broadcast).
__global__ __launch_bounds__(256) void k_output(const float* __restrict__ u_T,
                                                const float* __restrict__ Wm,
                                                const float* __restrict__ bias,
                                                const float* __restrict__ gamma,
                                                const float* __restrict__ beta,
                                                const float* __restrict__ VM,
                                                float* __restrict__ z,
                                                float* __restrict__ partial) {
    __shared__ float u_lds[E_ * B_];   // [e][b], 32 KB
    __shared__ float pex[B_];
    const int tid = threadIdx.x;
    for (int i = tid; i < (E_ * B_) / 4; i += 256)
        reinterpret_cast<float4*>(u_lds)[i] = reinterpret_cast<const float4*>(u_T)[i];
    if (tid < B_) pex[tid] = 0.f;
    __syncthreads();

    const int bg = tid & 7;            // batches bg*4 .. bg*4+3
    const int vl = tid >> 3;           // 0..31
    const int v = blockIdx.x * 32 + vl;
    const float* __restrict__ wr = Wm + (size_t)v * E_;

    float acc[4] = {0.f, 0.f, 0.f, 0.f};
    float4 wA[4], wB[4];
#pragma unroll
    for (int c = 0; c < 4; ++c) wA[c] = reinterpret_cast<const float4*>(wr)[c];

#pragma unroll 1
    for (int cc = 0; cc < 16; cc += 2) {
        // prefetch odd chunk
#pragma unroll
        for (int c = 0; c < 4; ++c) wB[c] = reinterpret_cast<const float4*>(wr)[(cc + 1) * 4 + c];
        // compute even chunk
#pragma unroll
        for (int c = 0; c < 4; ++c) {
#pragma unroll
            for (int q = 0; q < 4; ++q) {
                const int e = cc * 16 + c * 4 + q;
                const float4 u4 = *reinterpret_cast<const float4*>(&u_lds[e * B_ + bg * 4]);
                const float w = (q == 0) ? wA[c].x : (q == 1) ? wA[c].y : (q == 2) ? wA[c].z : wA[c].w;
                acc[0] += w * u4.x; acc[1] += w * u4.y; acc[2] += w * u4.z; acc[3] += w * u4.w;
            }
        }
        // prefetch next even chunk
        if (cc + 2 < 16) {
#pragma unroll
            for (int c = 0; c < 4; ++c) wA[c] = reinterpret_cast<const float4*>(wr)[(cc + 2) * 4 + c];
        }
        // compute odd chunk
#pragma unroll
        for (int c = 0; c < 4; ++c) {
#pragma unroll
            for (int q = 0; q < 4; ++q) {
                const int e = (cc + 1) * 16 + c * 4 + q;
                const float4 u4 = *reinterpret_cast<const float4*>(&u_lds[e * B_ + bg * 4]);
                const float w = (q == 0) ? wB[c].x : (q == 1) ? wB[c].y : (q == 2) ? wB[c].z : wB[c].w;
                acc[0] += w * u4.x; acc[1] += w * u4.y; acc[2] += w * u4.z; acc[3] += w * u4.w;
            }
        }
    }

    const float bv = bias[v];
    float s1 = 0.f, s2 = 0.f;
#pragma unroll
    for (int i = 0; i < 4; ++i) {
        acc[i] += bv;
        s1 += acc[i];
        s2 += acc[i] * acc[i];
    }
#pragma unroll
    for (int off = 1; off < 8; off <<= 1) {
        s1 += __shfl_xor(s1, off, 64);
        s2 += __shfl_xor(s2, off, 64);
    }
    const float mean = s1 * (1.0f / B_);
    const float var = s2 * (1.0f / B_) - mean * mean;
    const float rstd = rsqrtf(var + 1e-5f);
    const float g = gamma[v], be = beta[v];

    float exs = 0.f;
    float ex[4];
#pragma unroll
    for (int i = 0; i < 4; ++i) {
        const int b = bg * 4 + i;
        const size_t row = (size_t)b * V_ + v;
        const float vm = VM[row] + 1e-13f;
        const float y = g * (acc[i] - mean) * rstd + be;
        z[row] = y + logf(vm);
        ex[i] = vm * expf(y);
    }
#pragma unroll
    for (int i = 0; i < 4; ++i)
        atomicAdd(&pex[bg * 4 + i], ex[i]);
    (void)exs;
    __syncthreads();
    if (tid < B_) atomicAdd(&partial[tid * 8 + (blockIdx.x & 7)], pex[tid]);
}

// ---------------- Kernel 4: out = z - log(sum_s partial[b][s])
__global__ __launch_bounds__(256) void k_final(const float* __restrict__ z,
                                               const float* __restrict__ partial,
                                               float* __restrict__ out) {
    const int idx = blockIdx.x * 256 + threadIdx.x;
    const int b = idx / (V_ / 4);
    const int v4 = idx % (V_ / 4);
    float s = 0.f;
#pragma unroll
    for (int k = 0; k < 8; ++k) s += partial[b * 8 + k];
    const float lse = logf(s);
    const float4 x = reinterpret_cast<const float4*>(z + (size_t)b * V_)[v4];
    float4 o;
    o.x = x.x - lse; o.y = x.y - lse; o.z = x.z - lse; o.w = x.w - lse;
    reinterpret_cast<float4*>(out + (size_t)b * V_)[v4] = o;
}

extern "C" void kernel_launch(void* const* d_in, const int* in_sizes, int n_in,
                              void* d_out, int out_size, void* d_ws, size_t ws_size,
                              hipStream_t stream) {
    const int* trainS = (const int*)d_in[0];
    const int* trainQ = (const int*)d_in[1];
    const float* trainVM = (const float*)d_in[2];
    const float* trainPM = (const float*)d_in[3];
    const float* trainQM = (const float*)d_in[5];
    const float* A1 = (const float*)d_in[6];
    const float* A2 = (const float*)d_in[7];
    const float* A3 = (const float*)d_in[8];
    const float* A4 = (const float*)d_in[9];
    const float* Wm = (const float*)d_in[10];
    const float* bias = (const float*)d_in[11];
    const float* gamma = (const float*)d_in[12];
    const float* beta = (const float*)d_in[13];
    float* out = (float*)d_out;

    float* ws = (float*)d_ws;
    float* u_T = ws;                                 // E*B = 8192 (transposed [e][b])
    float* embA = ws + 8192;                         // 4*B*M*E
    float* z = embA + 4 * (B_ * M_ * E_);            // B*V
    float* partial = z + (size_t)B_ * V_;            // 32*8 = 256

    k_embed<<<B_ * M_, 256, 0, stream>>>(trainS, A1, A2, A3, A4, embA);
    k_hops<<<B_, 1024, 0, stream>>>(trainQ, trainQM, A1, embA, trainPM, u_T, partial);
    k_output<<<V_ / 32, 256, 0, stream>>>(u_T, Wm, bias, gamma, beta, trainVM, z, partial);
    k_final<<<(B_ * V_ / 4) / 256, 256, 0, stream>>>(z, partial, out);
}

// Round 9
// 115.326 us; speedup vs baseline: 1.0485x; 1.0485x over previous
//
#include <hip/hip_runtime.h>
#include <math.h>

static constexpr int B_ = 32, M_ = 100, L_ = 30, LQ_ = 30, E_ = 256, V_ = 32000;

// ---------------- Kernel 1: story embeddings (fused 4 tables; 66us request-rate wall).
__global__ __launch_bounds__(256) void k_embed(const int* __restrict__ trainS,
                                               const float* __restrict__ A1,
                                               const float* __restrict__ A2,
                                               const float* __restrict__ A3,
                                               const float* __restrict__ A4,
                                               float* __restrict__ embA) {
    const int bm = blockIdx.x;
    const int tbl = threadIdx.x >> 6;
    const int e0 = (threadIdx.x & 63) * 4;
    const float* __restrict__ A = (tbl == 0) ? A1 : (tbl == 1) ? A2 : (tbl == 2) ? A3 : A4;
    const float half_e = (E_ + 1) * 0.5f;
    const float half_j = (L_ + 1) * 0.5f;
    const float inv = 1.0f / (float)(E_ * L_);
    const float k0 = (float)(e0 + 1) - half_e;
    const float k1 = k0 + 1.f, k2 = k0 + 2.f, k3 = k0 + 3.f;

    int idx[L_];
#pragma unroll
    for (int l = 0; l < L_; ++l) idx[l] = trainS[bm * L_ + l];

    float4 acc = make_float4(0.f, 0.f, 0.f, 0.f);
#pragma unroll
    for (int c = 0; c < 2; ++c) {
        float4 r[15];
#pragma unroll
        for (int j = 0; j < 15; ++j)
            r[j] = *reinterpret_cast<const float4*>(A + (size_t)idx[c * 15 + j] * E_ + e0);
        __builtin_amdgcn_sched_barrier(0);
#pragma unroll
        for (int j = 0; j < 15; ++j) {
            const int l = c * 15 + j;
            const float coef = 4.0f * ((float)(l + 1) - half_j) * inv;
            acc.x += r[j].x * (1.0f + coef * k0);
            acc.y += r[j].y * (1.0f + coef * k1);
            acc.z += r[j].z * (1.0f + coef * k2);
            acc.w += r[j].w * (1.0f + coef * k3);
        }
    }
    *reinterpret_cast<float4*>(embA + (size_t)tbl * (B_ * M_ * E_) + (size_t)bm * E_ + e0) = acc;
}

// ---------------- Kernel 2: query embedding + three hops. One 1024-thread block per b.
// Writes u TRANSPOSED u_T[e*B + b]; zeroes partial[b*8..b*8+7].
__global__ __launch_bounds__(1024) void k_hops(const int* __restrict__ trainQ,
                                               const float* __restrict__ trainQM,
                                               const float* __restrict__ A1,
                                               const float* __restrict__ embA,
                                               const float* __restrict__ trainPM,
                                               float* __restrict__ u_T,
                                               float* __restrict__ partial) {
    const int b = blockIdx.x;
    const int tid = threadIdx.x;
    const int lane = tid & 63;
    const int wave = tid >> 6;
    const int g = tid >> 8;
    const int e = tid & 255;
    if (tid < 8) partial[b * 8 + tid] = 0.f;
    __shared__ float u_sh[E_];
    __shared__ float sc[M_];
    __shared__ float p_sh[M_];
    __shared__ float osum[4][E_];

    {
        const float half_e = (E_ + 1) * 0.5f;
        const float half_j = (LQ_ + 1) * 0.5f;
        const float inv = 1.0f / (float)(E_ * LQ_);
        const float ke = (float)(e + 1) - half_e;
        const int l0 = g * 8;
        const int ln = (LQ_ - l0 < 8) ? (LQ_ - l0) : 8;
        int qi[8];
        float qm[8];
#pragma unroll
        for (int j = 0; j < 8; ++j) {
            if (j < ln) {
                qi[j] = trainQ[b * LQ_ + l0 + j];
                qm[j] = trainQM[b * LQ_ + l0 + j];
            } else { qi[j] = 0; qm[j] = 0.f; }
        }
        float r[8];
#pragma unroll
        for (int j = 0; j < 8; ++j)
            r[j] = (j < ln) ? A1[(size_t)qi[j] * E_ + e] : 0.f;
        float part = 0.f;
#pragma unroll
        for (int j = 0; j < 8; ++j) {
            const float pe = 1.0f + 4.0f * ke * ((float)(l0 + j + 1) - half_j) * inv;
            part += r[j] * pe * qm[j];
        }
        osum[g][e] = part;
    }
    __syncthreads();
    if (tid < E_) u_sh[tid] = osum[0][tid] + osum[1][tid] + osum[2][tid] + osum[3][tid];
    __syncthreads();

    for (int hop = 0; hop < 3; ++hop) {
        const float* memA = embA + (size_t)hop * (B_ * M_ * E_) + (size_t)b * M_ * E_;
        const float* memC = memA + (size_t)(B_ * M_ * E_);
#pragma unroll 2
        for (int m = wave; m < M_; m += 16) {
            const float* row = memA + m * E_;
            float part = 0.f;
#pragma unroll
            for (int j = 0; j < 4; ++j)
                part += row[lane + 64 * j] * u_sh[lane + 64 * j];
#pragma unroll
            for (int off = 32; off > 0; off >>= 1)
                part += __shfl_xor(part, off, 64);
            if (lane == 0) sc[m] = part * trainPM[b * M_ + m];
        }
        __syncthreads();
        if (wave == 0) {
            const float pm0 = (lane < M_) ? trainPM[b * M_ + lane] : 0.f;
            const float pm1 = (lane + 64 < M_) ? trainPM[b * M_ + lane + 64] : 0.f;
            const float x0 = (lane < M_ && pm0 > 0.f) ? sc[lane] : -1e30f;
            const float x1 = (lane + 64 < M_ && pm1 > 0.f) ? sc[lane + 64] : -1e30f;
            float mx = fmaxf(x0, x1);
#pragma unroll
            for (int off = 32; off > 0; off >>= 1)
                mx = fmaxf(mx, __shfl_xor(mx, off, 64));
            const float e0v = (lane < M_) ? expf(x0 - mx) * pm0 : 0.f;
            const float e1v = (lane + 64 < M_) ? expf(x1 - mx) * pm1 : 0.f;
            float ssum = e0v + e1v;
#pragma unroll
            for (int off = 32; off > 0; off >>= 1)
                ssum += __shfl_xor(ssum, off, 64);
            const float invs = 1.0f / (ssum + 1e-13f);
            if (lane < M_) p_sh[lane] = e0v * invs;
            if (lane + 64 < M_) p_sh[lane + 64] = e1v * invs;
        }
        __syncthreads();
        {
            float acc = 0.f;
            const float* crow = memC + e;
            const int m0 = g * 25;
#pragma unroll 5
            for (int mm = 0; mm < 25; ++mm)
                acc += p_sh[m0 + mm] * crow[(size_t)(m0 + mm) * E_];
            osum[g][e] = acc;
        }
        __syncthreads();
        if (tid < E_) u_sh[tid] += osum[0][tid] + osum[1][tid] + osum[2][tid] + osum[3][tid];
        __syncthreads();
    }
    if (tid < E_) u_T[tid * B_ + b] = u_sh[tid];
}

// ---------------- Kernel 3: wx = u @ W.T + b; batch-LN; z = y + log(VM); exp-partials.
// Vt=2 (2 v x 4 b per thread), 64 v/block, grid 500. W stream software-pipelined:
// depth-2 register dbuf at 8-e stages (8 float4 in flight), rolled loop, no sched_barrier.
#define COMPUTE8(W0A, W0B, W1A, W1B, EBASE)                                          \
    {                                                                                \
        _Pragma("unroll")                                                            \
        for (int q = 0; q < 8; ++q) {                                                \
            const float4 u4 = *reinterpret_cast<const float4*>(                      \
                &u_lds[((EBASE) + q) * B_ + bg * 4]);                                \
            const float w0 = (q < 4) ? ((q == 0) ? (W0A).x : (q == 1) ? (W0A).y      \
                                        : (q == 2) ? (W0A).z : (W0A).w)              \
                                     : ((q == 4) ? (W0B).x : (q == 5) ? (W0B).y      \
                                        : (q == 6) ? (W0B).z : (W0B).w);             \
            const float w1 = (q < 4) ? ((q == 0) ? (W1A).x : (q == 1) ? (W1A).y      \
                                        : (q == 2) ? (W1A).z : (W1A).w)              \
                                     : ((q == 4) ? (W1B).x : (q == 5) ? (W1B).y      \
                                        : (q == 6) ? (W1B).z : (W1B).w);             \
            acc0[0] += w0 * u4.x; acc0[1] += w0 * u4.y;                              \
            acc0[2] += w0 * u4.z; acc0[3] += w0 * u4.w;                              \
            acc1[0] += w1 * u4.x; acc1[1] += w1 * u4.y;                              \
            acc1[2] += w1 * u4.z; acc1[3] += w1 * u4.w;                              \
        }                                                                            \
    }

__global__ __launch_bounds__(256) void k_output(const float* __restrict__ u_T,
                                                const float* __restrict__ Wm,
                                                const float* __restrict__ bias,
                                                const float* __restrict__ gamma,
                                                const float* __restrict__ beta,
                                                const float* __restrict__ VM,
                                                float* __restrict__ z,
                                                float* __restrict__ partial) {
    __shared__ float u_lds[E_ * B_];   // [e][b], 32 KB
    __shared__ float pex[B_];
    const int tid = threadIdx.x;
    for (int i = tid; i < (E_ * B_) / 4; i += 256)
        reinterpret_cast<float4*>(u_lds)[i] = reinterpret_cast<const float4*>(u_T)[i];
    if (tid < B_) pex[tid] = 0.f;
    __syncthreads();

    const int bg = tid & 7;            // batches bg*4 .. bg*4+3
    const int vl = tid >> 3;           // 0..31
    const int v0 = blockIdx.x * 64 + vl * 2;
    const int v1 = v0 + 1;
    const float4* __restrict__ wp0 = reinterpret_cast<const float4*>(Wm + (size_t)v0 * E_);
    const float4* __restrict__ wp1 = reinterpret_cast<const float4*>(Wm + (size_t)v1 * E_);

    float acc0[4] = {0.f, 0.f, 0.f, 0.f};
    float acc1[4] = {0.f, 0.f, 0.f, 0.f};

    // 32 stages of 8 e (2 float4 per v per stage); depth-2 ping-pong dbuf.
    float4 A0a = wp0[0], A0b = wp0[1], A1a = wp1[0], A1b = wp1[1];
    float4 B0a, B0b, B1a, B1b;
#pragma unroll 1
    for (int s = 0; s < 32; s += 2) {
        B0a = wp0[(s + 1) * 2]; B0b = wp0[(s + 1) * 2 + 1];
        B1a = wp1[(s + 1) * 2]; B1b = wp1[(s + 1) * 2 + 1];
        COMPUTE8(A0a, A0b, A1a, A1b, s * 8);
        if (s + 2 < 32) {
            A0a = wp0[(s + 2) * 2]; A0b = wp0[(s + 2) * 2 + 1];
            A1a = wp1[(s + 2) * 2]; A1b = wp1[(s + 2) * 2 + 1];
        }
        COMPUTE8(B0a, B0b, B1a, B1b, (s + 1) * 8);
    }

    const float bv0 = bias[v0], bv1 = bias[v1];
    float s1a = 0.f, s2a = 0.f, s1b = 0.f, s2b = 0.f;
#pragma unroll
    for (int i = 0; i < 4; ++i) {
        acc0[i] += bv0; acc1[i] += bv1;
        s1a += acc0[i]; s2a += acc0[i] * acc0[i];
        s1b += acc1[i]; s2b += acc1[i] * acc1[i];
    }
#pragma unroll
    for (int off = 1; off < 8; off <<= 1) {
        s1a += __shfl_xor(s1a, off, 64);
        s2a += __shfl_xor(s2a, off, 64);
        s1b += __shfl_xor(s1b, off, 64);
        s2b += __shfl_xor(s2b, off, 64);
    }
    const float meanA = s1a * (1.0f / B_);
    const float meanB = s1b * (1.0f / B_);
    const float varA = s2a * (1.0f / B_) - meanA * meanA;
    const float varB = s2b * (1.0f / B_) - meanB * meanB;
    const float rstdA = rsqrtf(varA + 1e-5f);
    const float rstdB = rsqrtf(varB + 1e-5f);
    const float gA = gamma[v0], beA = beta[v0];
    const float gB = gamma[v1], beB = beta[v1];

    float ex[4];
#pragma unroll
    for (int i = 0; i < 4; ++i) {
        const int b = bg * 4 + i;
        const size_t row = (size_t)b * V_;
        const float vm0 = VM[row + v0] + 1e-13f;
        const float vm1 = VM[row + v1] + 1e-13f;
        const float y0 = gA * (acc0[i] - meanA) * rstdA + beA;
        const float y1 = gB * (acc1[i] - meanB) * rstdB + beB;
        z[row + v0] = y0 + logf(vm0);
        z[row + v1] = y1 + logf(vm1);
        ex[i] = vm0 * expf(y0) + vm1 * expf(y1);
    }
#pragma unroll
    for (int i = 0; i < 4; ++i)
        atomicAdd(&pex[bg * 4 + i], ex[i]);
    __syncthreads();
    if (tid < B_) atomicAdd(&partial[tid * 8 + (blockIdx.x & 7)], pex[tid]);
}

// ---------------- Kernel 4: out = z - log(sum_s partial[b][s])
__global__ __launch_bounds__(256) void k_final(const float* __restrict__ z,
                                               const float* __restrict__ partial,
                                               float* __restrict__ out) {
    const int idx = blockIdx.x * 256 + threadIdx.x;
    const int b = idx / (V_ / 4);
    const int v4 = idx % (V_ / 4);
    float s = 0.f;
#pragma unroll
    for (int k = 0; k < 8; ++k) s += partial[b * 8 + k];
    const float lse = logf(s);
    const float4 x = reinterpret_cast<const float4*>(z + (size_t)b * V_)[v4];
    float4 o;
    o.x = x.x - lse; o.y = x.y - lse; o.z = x.z - lse; o.w = x.w - lse;
    reinterpret_cast<float4*>(out + (size_t)b * V_)[v4] = o;
}

extern "C" void kernel_launch(void* const* d_in, const int* in_sizes, int n_in,
                              void* d_out, int out_size, void* d_ws, size_t ws_size,
                              hipStream_t stream) {
    const int* trainS = (const int*)d_in[0];
    const int* trainQ = (const int*)d_in[1];
    const float* trainVM = (const float*)d_in[2];
    const float* trainPM = (const float*)d_in[3];
    const float* trainQM = (const float*)d_in[5];
    const float* A1 = (const float*)d_in[6];
    const float* A2 = (const float*)d_in[7];
    const float* A3 = (const float*)d_in[8];
    const float* A4 = (const float*)d_in[9];
    const float* Wm = (const float*)d_in[10];
    const float* bias = (const float*)d_in[11];
    const float* gamma = (const float*)d_in[12];
    const float* beta = (const float*)d_in[13];
    float* out = (float*)d_out;

    float* ws = (float*)d_ws;
    float* u_T = ws;                                 // E*B = 8192 (transposed [e][b])
    float* embA = ws + 8192;                         // 4*B*M*E
    float* z = embA + 4 * (B_ * M_ * E_);            // B*V
    float* partial = z + (size_t)B_ * V_;            // 32*8 = 256

    k_embed<<<B_ * M_, 256, 0, stream>>>(trainS, A1, A2, A3, A4, embA);
    k_hops<<<B_, 1024, 0, stream>>>(trainQ, trainQM, A1, embA, trainPM, u_T, partial);
    k_output<<<V_ / 64, 256, 0, stream>>>(u_T, Wm, bias, gamma, beta, trainVM, z, partial);
    k_final<<<(B_ * V_ / 4) / 256, 256, 0, stream>>>(z, partial, out);
}

// Round 10
// 108.940 us; speedup vs baseline: 1.1100x; 1.0586x over previous
//
#include <hip/hip_runtime.h>
#include <math.h>

static constexpr int B_ = 32, M_ = 100, L_ = 30, LQ_ = 30, E_ = 256, V_ = 32000;

typedef __attribute__((ext_vector_type(8))) short bf16x8;
typedef __attribute__((ext_vector_type(4))) float f32x4;

__device__ __forceinline__ unsigned f2bf(float f) {   // RNE f32 -> bf16 bits
    unsigned u = __float_as_uint(f);
    return (u + 0x7FFFu + ((u >> 16) & 1u)) >> 16;
}

// ---------------- Kernel 1: story embeddings (fused 4 tables; 66us request-rate wall).
__global__ __launch_bounds__(256) void k_embed(const int* __restrict__ trainS,
                                               const float* __restrict__ A1,
                                               const float* __restrict__ A2,
                                               const float* __restrict__ A3,
                                               const float* __restrict__ A4,
                                               float* __restrict__ embA) {
    const int bm = blockIdx.x;
    const int tbl = threadIdx.x >> 6;
    const int e0 = (threadIdx.x & 63) * 4;
    const float* __restrict__ A = (tbl == 0) ? A1 : (tbl == 1) ? A2 : (tbl == 2) ? A3 : A4;
    const float half_e = (E_ + 1) * 0.5f;
    const float half_j = (L_ + 1) * 0.5f;
    const float inv = 1.0f / (float)(E_ * L_);
    const float k0 = (float)(e0 + 1) - half_e;
    const float k1 = k0 + 1.f, k2 = k0 + 2.f, k3 = k0 + 3.f;

    int idx[L_];
#pragma unroll
    for (int l = 0; l < L_; ++l) idx[l] = trainS[bm * L_ + l];

    float4 acc = make_float4(0.f, 0.f, 0.f, 0.f);
#pragma unroll
    for (int c = 0; c < 2; ++c) {
        float4 r[15];
#pragma unroll
        for (int j = 0; j < 15; ++j)
            r[j] = *reinterpret_cast<const float4*>(A + (size_t)idx[c * 15 + j] * E_ + e0);
        __builtin_amdgcn_sched_barrier(0);
#pragma unroll
        for (int j = 0; j < 15; ++j) {
            const int l = c * 15 + j;
            const float coef = 4.0f * ((float)(l + 1) - half_j) * inv;
            acc.x += r[j].x * (1.0f + coef * k0);
            acc.y += r[j].y * (1.0f + coef * k1);
            acc.z += r[j].z * (1.0f + coef * k2);
            acc.w += r[j].w * (1.0f + coef * k3);
        }
    }
    *reinterpret_cast<float4*>(embA + (size_t)tbl * (B_ * M_ * E_) + (size_t)bm * E_ + e0) = acc;
}

// ---------------- Kernel 2: query embedding + three hops. One 1024-thread block per b.
// Writes u in NORMAL layout u_N[b*E+e]; zeroes partial[b*8..b*8+7].
__global__ __launch_bounds__(1024) void k_hops(const int* __restrict__ trainQ,
                                               const float* __restrict__ trainQM,
                                               const float* __restrict__ A1,
                                               const float* __restrict__ embA,
                                               const float* __restrict__ trainPM,
                                               float* __restrict__ u_N,
                                               float* __restrict__ partial) {
    const int b = blockIdx.x;
    const int tid = threadIdx.x;
    const int lane = tid & 63;
    const int wave = tid >> 6;
    const int g = tid >> 8;
    const int e = tid & 255;
    if (tid < 8) partial[b * 8 + tid] = 0.f;
    __shared__ float u_sh[E_];
    __shared__ float sc[M_];
    __shared__ float p_sh[M_];
    __shared__ float osum[4][E_];

    {
        const float half_e = (E_ + 1) * 0.5f;
        const float half_j = (LQ_ + 1) * 0.5f;
        const float inv = 1.0f / (float)(E_ * LQ_);
        const float ke = (float)(e + 1) - half_e;
        const int l0 = g * 8;
        const int ln = (LQ_ - l0 < 8) ? (LQ_ - l0) : 8;
        int qi[8];
        float qm[8];
#pragma unroll
        for (int j = 0; j < 8; ++j) {
            if (j < ln) {
                qi[j] = trainQ[b * LQ_ + l0 + j];
                qm[j] = trainQM[b * LQ_ + l0 + j];
            } else { qi[j] = 0; qm[j] = 0.f; }
        }
        float r[8];
#pragma unroll
        for (int j = 0; j < 8; ++j)
            r[j] = (j < ln) ? A1[(size_t)qi[j] * E_ + e] : 0.f;
        float part = 0.f;
#pragma unroll
        for (int j = 0; j < 8; ++j) {
            const float pe = 1.0f + 4.0f * ke * ((float)(l0 + j + 1) - half_j) * inv;
            part += r[j] * pe * qm[j];
        }
        osum[g][e] = part;
    }
    __syncthreads();
    if (tid < E_) u_sh[tid] = osum[0][tid] + osum[1][tid] + osum[2][tid] + osum[3][tid];
    __syncthreads();

    for (int hop = 0; hop < 3; ++hop) {
        const float* memA = embA + (size_t)hop * (B_ * M_ * E_) + (size_t)b * M_ * E_;
        const float* memC = memA + (size_t)(B_ * M_ * E_);
#pragma unroll 2
        for (int m = wave; m < M_; m += 16) {
            const float* row = memA + m * E_;
            float part = 0.f;
#pragma unroll
            for (int j = 0; j < 4; ++j)
                part += row[lane + 64 * j] * u_sh[lane + 64 * j];
#pragma unroll
            for (int off = 32; off > 0; off >>= 1)
                part += __shfl_xor(part, off, 64);
            if (lane == 0) sc[m] = part * trainPM[b * M_ + m];
        }
        __syncthreads();
        if (wave == 0) {
            const float pm0 = (lane < M_) ? trainPM[b * M_ + lane] : 0.f;
            const float pm1 = (lane + 64 < M_) ? trainPM[b * M_ + lane + 64] : 0.f;
            const float x0 = (lane < M_ && pm0 > 0.f) ? sc[lane] : -1e30f;
            const float x1 = (lane + 64 < M_ && pm1 > 0.f) ? sc[lane + 64] : -1e30f;
            float mx = fmaxf(x0, x1);
#pragma unroll
            for (int off = 32; off > 0; off >>= 1)
                mx = fmaxf(mx, __shfl_xor(mx, off, 64));
            const float e0v = (lane < M_) ? expf(x0 - mx) * pm0 : 0.f;
            const float e1v = (lane + 64 < M_) ? expf(x1 - mx) * pm1 : 0.f;
            float ssum = e0v + e1v;
#pragma unroll
            for (int off = 32; off > 0; off >>= 1)
                ssum += __shfl_xor(ssum, off, 64);
            const float invs = 1.0f / (ssum + 1e-13f);
            if (lane < M_) p_sh[lane] = e0v * invs;
            if (lane + 64 < M_) p_sh[lane + 64] = e1v * invs;
        }
        __syncthreads();
        {
            float acc = 0.f;
            const float* crow = memC + e;
            const int m0 = g * 25;
#pragma unroll 5
            for (int mm = 0; mm < 25; ++mm)
                acc += p_sh[m0 + mm] * crow[(size_t)(m0 + mm) * E_];
            osum[g][e] = acc;
        }
        __syncthreads();
        if (tid < E_) u_sh[tid] += osum[0][tid] + osum[1][tid] + osum[2][tid] + osum[3][tid];
        __syncthreads();
    }
    if (tid < E_) u_N[b * E_ + tid] = u_sh[tid];
}

// ---------------- Kernel 3: MFMA GEMM (M=32,K=256,N=32000) + batch-LN + log(VM) + exp-partials.
// Block = 4 waves; wave w: 16 cols n0=(blk*4+w)*16, both 16-row m-tiles; 16x mfma_f32_16x16x32_bf16.
// u staged in LDS bf16 [m][k], 16B-granule XOR swizzle; W frags reg-loaded (16 float4 upfront).
// bias omitted: cancels exactly through batch-mean subtraction.
__global__ __launch_bounds__(256) void k_output(const float* __restrict__ u_N,
                                                const float* __restrict__ Wm,
                                                const float* __restrict__ gamma,
                                                const float* __restrict__ beta,
                                                const float* __restrict__ VM,
                                                float* __restrict__ z,
                                                float* __restrict__ partial) {
    __shared__ char uAraw[32 * 512];   // [m] rows, 512B each: bf16 u[m][k], swizzled 16B granules
    __shared__ float pex[B_];
    const int tid = threadIdx.x;
    {
        const int m = tid >> 3;
        const int kc = (tid & 7) * 32;
        const float4* src = reinterpret_cast<const float4*>(u_N + m * E_ + kc);
#pragma unroll
        for (int j = 0; j < 4; ++j) {
            const float4 f0 = src[2 * j];
            const float4 f1 = src[2 * j + 1];
            uint4 q;
            q.x = f2bf(f0.x) | (f2bf(f0.y) << 16);
            q.y = f2bf(f0.z) | (f2bf(f0.w) << 16);
            q.z = f2bf(f1.x) | (f2bf(f1.y) << 16);
            q.w = f2bf(f1.z) | (f2bf(f1.w) << 16);
            const int k16 = kc / 8 + j;
            const int off = m * 512 + ((k16 * 16) ^ ((m & 7) << 4));
            *reinterpret_cast<uint4*>(uAraw + off) = q;
        }
    }
    if (tid < B_) pex[tid] = 0.f;
    __syncthreads();

    const int lane = tid & 63;
    const int wv = tid >> 6;
    const int col = lane & 15;
    const int grp = lane >> 4;
    const int n0 = (blockIdx.x * 4 + wv) * 16;
    const int v = n0 + col;

    // ---- load all W fragments upfront: lane covers row v, k = s*32 + grp*8 .. +7
    float4 wreg[16];
    {
        const float* wrow = Wm + (size_t)v * E_ + grp * 8;
#pragma unroll
        for (int s = 0; s < 8; ++s) {
            wreg[2 * s] = *reinterpret_cast<const float4*>(wrow + s * 32);
            wreg[2 * s + 1] = *reinterpret_cast<const float4*>(wrow + s * 32 + 4);
        }
    }
    __builtin_amdgcn_sched_barrier(0);

    // ---- load all A fragments: af[mt][s] = u[mt*16+col][s*32+grp*8 ..+7]
    bf16x8 af[2][8];
#pragma unroll
    for (int mt = 0; mt < 2; ++mt) {
        const int m = mt * 16 + col;
#pragma unroll
        for (int s = 0; s < 8; ++s) {
            const int k16 = s * 4 + grp;
            const int off = m * 512 + ((k16 * 16) ^ ((m & 7) << 4));
            af[mt][s] = *reinterpret_cast<bf16x8*>(uAraw + off);
        }
    }

    // ---- MFMA K-loop
    f32x4 acc0 = {0.f, 0.f, 0.f, 0.f};
    f32x4 acc1 = {0.f, 0.f, 0.f, 0.f};
#pragma unroll
    for (int s = 0; s < 8; ++s) {
        const float4 w0 = wreg[2 * s], w1 = wreg[2 * s + 1];
        bf16x8 bf;
        bf[0] = (short)f2bf(w0.x); bf[1] = (short)f2bf(w0.y);
        bf[2] = (short)f2bf(w0.z); bf[3] = (short)f2bf(w0.w);
        bf[4] = (short)f2bf(w1.x); bf[5] = (short)f2bf(w1.y);
        bf[6] = (short)f2bf(w1.z); bf[7] = (short)f2bf(w1.w);
        acc0 = __builtin_amdgcn_mfma_f32_16x16x32_bf16(af[0][s], bf, acc0, 0, 0, 0);
        acc1 = __builtin_amdgcn_mfma_f32_16x16x32_bf16(af[1][s], bf, acc1, 0, 0, 0);
    }

    // ---- batch-LN stats for col v: local 8 accs + shfl over the 4 lane-groups
    float s1 = 0.f, s2 = 0.f;
#pragma unroll
    for (int r = 0; r < 4; ++r) {
        s1 += acc0[r] + acc1[r];
        s2 += acc0[r] * acc0[r] + acc1[r] * acc1[r];
    }
    s1 += __shfl_xor(s1, 16, 64);
    s2 += __shfl_xor(s2, 16, 64);
    s1 += __shfl_xor(s1, 32, 64);
    s2 += __shfl_xor(s2, 32, 64);
    const float mean = s1 * (1.0f / B_);
    const float var = s2 * (1.0f / B_) - mean * mean;
    const float rstd = rsqrtf(var + 1e-5f);
    const float gg = gamma[v], be = beta[v];

    // ---- z writes + exp partials. b = mt*16 + grp*4 + r (C/D: col=lane&15, row=(lane>>4)*4+r)
#pragma unroll
    for (int mt = 0; mt < 2; ++mt) {
#pragma unroll
        for (int r = 0; r < 4; ++r) {
            const int b = mt * 16 + grp * 4 + r;
            const float wx = (mt == 0) ? acc0[r] : acc1[r];
            const float y = gg * (wx - mean) * rstd + be;
            const size_t row = (size_t)b * V_ + v;
            const float vm = VM[row] + 1e-13f;
            z[row] = y + logf(vm);
            atomicAdd(&pex[b], vm * expf(y));
        }
    }
    __syncthreads();
    if (tid < B_) atomicAdd(&partial[tid * 8 + (blockIdx.x & 7)], pex[tid]);
}

// ---------------- Kernel 4: out = z - log(sum_s partial[b][s])
__global__ __launch_bounds__(256) void k_final(const float* __restrict__ z,
                                               const float* __restrict__ partial,
                                               float* __restrict__ out) {
    const int idx = blockIdx.x * 256 + threadIdx.x;
    const int b = idx / (V_ / 4);
    const int v4 = idx % (V_ / 4);
    float s = 0.f;
#pragma unroll
    for (int k = 0; k < 8; ++k) s += partial[b * 8 + k];
    const float lse = logf(s);
    const float4 x = reinterpret_cast<const float4*>(z + (size_t)b * V_)[v4];
    float4 o;
    o.x = x.x - lse; o.y = x.y - lse; o.z = x.z - lse; o.w = x.w - lse;
    reinterpret_cast<float4*>(out + (size_t)b * V_)[v4] = o;
}

extern "C" void kernel_launch(void* const* d_in, const int* in_sizes, int n_in,
                              void* d_out, int out_size, void* d_ws, size_t ws_size,
                              hipStream_t stream) {
    const int* trainS = (const int*)d_in[0];
    const int* trainQ = (const int*)d_in[1];
    const float* trainVM = (const float*)d_in[2];
    const float* trainPM = (const float*)d_in[3];
    const float* trainQM = (const float*)d_in[5];
    const float* A1 = (const float*)d_in[6];
    const float* A2 = (const float*)d_in[7];
    const float* A3 = (const float*)d_in[8];
    const float* A4 = (const float*)d_in[9];
    const float* Wm = (const float*)d_in[10];
    const float* gamma = (const float*)d_in[12];
    const float* beta = (const float*)d_in[13];
    float* out = (float*)d_out;

    float* ws = (float*)d_ws;
    float* u_N = ws;                                 // B*E = 8192
    float* embA = ws + 8192;                         // 4*B*M*E
    float* z = embA + 4 * (B_ * M_ * E_);            // B*V
    float* partial = z + (size_t)B_ * V_;            // 32*8 = 256

    k_embed<<<B_ * M_, 256, 0, stream>>>(trainS, A1, A2, A3, A4, embA);
    k_hops<<<B_, 1024, 0, stream>>>(trainQ, trainQM, A1, embA, trainPM, u_N, partial);
    k_output<<<V_ / 64, 256, 0, stream>>>(u_N, Wm, gamma, beta, trainVM, z, partial);
    k_final<<<(B_ * V_ / 4) / 256, 256, 0, stream>>>(z, partial, out);
}